// Round 11
// baseline (369.093 us; speedup 1.0000x reference)
//
#include <hip/hip_runtime.h>

#define NN 100000
#define NE 1600000
#define HH 32
#define CC 10
#define GG 64
#define NB 391
#define PBLK 160
#define ECH 10000
#define MTOT (NB * PBLK)
#define MSB ((MTOT + 255) / 256)

typedef _Float16 half8 __attribute__((ext_vector_type(8)));
typedef _Float16 half2v __attribute__((ext_vector_type(2)));
typedef float f32x4 __attribute__((ext_vector_type(4)));

__device__ __forceinline__ half2v bch(int v) { return __builtin_bit_cast(half2v, v); }

// K-permutation shared by edgeconv stores, Mfrag build, and fold_mfma:
// knew = p*64 + jch*2 + s  <->  korig = (2p+s)*32 + jch   (class = 2p+s, channel = jch)
// MFMA sums over K, so any consistent permutation is exact.

__global__ void precompute_small(const float* __restrict__ fW, const float* __restrict__ fb,
                                 const float* __restrict__ W1, const float* __restrict__ b1,
                                 const float* __restrict__ W2, const float* __restrict__ b2,
                                 const float* __restrict__ g1W, float* __restrict__ tab,
                                 _Float16* __restrict__ Mfrag) {
    int c = blockIdx.x;
    int k = threadIdx.x >> 5;
    int j = threadIdx.x & 31;
    float m = 0.f;
    for (int mm = 0; mm < 32; ++mm)
        m += W2[k * 32 + mm] * g1W[(3 + 32 * c + mm) * 32 + j];
    tab[2240 + c * 1024 + k * 32 + j] = m;

    if (k < 3) {
        float a = 0.f, b = 0.f;
        for (int i = 0; i < 32; ++i) {
            float w = fW[c * 96 + k * 32 + i];
            a += w * W1[i * 32 + j];
            b += w * W1[(32 + i) * 32 + j];
        }
        tab[c * 96 + k * 32 + j] = a;
        tab[960 + c * 96 + k * 32 + j] = b;
    } else if (k == 3) {
        float h = b1[j];
        for (int i = 0; i < 32; ++i)
            h += fb[c * 32 + i] * (W1[i * 32 + j] + W1[(32 + i) * 32 + j]);
        tab[1920 + c * 32 + j] = h;
    } else if (k == 4 && c == 0) {
        float t = 0.f;
        for (int cc2 = 0; cc2 < CC; ++cc2)
            for (int mm = 0; mm < 32; ++mm)
                t += b2[mm] * g1W[(3 + 32 * cc2 + mm) * 32 + j];
        tab[12480 + j] = t;
    }
    __syncthreads();
    // Mfrag entries whose K-row belongs to class c (this block computed those rows above).
    {
        int jch = k;
        int jcol = j;
        float v = tab[2240 + c * 1024 + jch * 32 + jcol];
        int knew = (c >> 1) * 64 + 2 * jch + (c & 1);
        int kc = knew >> 5, within = knew & 31;
        int jt = jcol >> 4;
        int lq = within >> 3, ii = within & 7;
        int lidx = lq * 16 + (jcol & 15);
        int flat = ((kc * 2 + jt) * 64 + lidx) * 8 + ii;
        Mfrag[flat] = (_Float16)v;
    }
}

// ---- atomic-free CSR build (bucket two-phase: scatter locality, r8 lesson) ----
__global__ void bucket_hist(const int* __restrict__ ei, int* __restrict__ mat) {
    __shared__ int h[NB];
    int blk = blockIdx.x, tid = threadIdx.x;
    for (int i = tid; i < NB; i += 256) h[i] = 0;
    __syncthreads();
    int base = blk * ECH;
    for (int k = tid; k < ECH; k += 256)
        atomicAdd(&h[ei[NE + base + k] >> 8], 1);
    __syncthreads();
    for (int i = tid; i < NB; i += 256) mat[i * PBLK + blk] = h[i];
}

__global__ void scan_m1(const int* __restrict__ mat, int* __restrict__ msum) {
    __shared__ int sh[256];
    int b = blockIdx.x, t = threadIdx.x;
    int i = b * 256 + t;
    sh[t] = (i < MTOT) ? mat[i] : 0;
    __syncthreads();
    for (int off = 128; off > 0; off >>= 1) {
        if (t < off) sh[t] += sh[t + off];
        __syncthreads();
    }
    if (t == 0) msum[b] = sh[0];
}

__global__ void scan_m2(int* __restrict__ msum, float* __restrict__ pooled) {
    // also zero pooled+counts (GG*33 floats) -- absorbed zero_f kernel
    for (int i = threadIdx.x; i < GG * 33; i += 256) pooled[i] = 0.0f;
    __shared__ int sh[256];
    int t = threadIdx.x;
    int v = (t < MSB) ? msum[t] : 0;
    sh[t] = v;
    __syncthreads();
    for (int off = 1; off < 256; off <<= 1) {
        int add = (t >= off) ? sh[t - off] : 0;
        __syncthreads();
        sh[t] += add;
        __syncthreads();
    }
    if (t < MSB) msum[t] = sh[t] - v;
}

__global__ void scan_m3(int* __restrict__ mat, const int* __restrict__ msum) {
    __shared__ int sh[256];
    int b = blockIdx.x, t = threadIdx.x;
    int i = b * 256 + t;
    int v = (i < MTOT) ? mat[i] : 0;
    sh[t] = v;
    __syncthreads();
    for (int off = 1; off < 256; off <<= 1) {
        int add = (t >= off) ? sh[t - off] : 0;
        __syncthreads();
        sh[t] += add;
        __syncthreads();
    }
    if (i < MTOT) mat[i] = sh[t] - v + msum[b];
}

__global__ void bucket_scatter(const int* __restrict__ ei, const int* __restrict__ mat,
                               unsigned int* __restrict__ part) {
    __shared__ int bas[NB];
    __shared__ int cur[NB];
    int blk = blockIdx.x, tid = threadIdx.x;
    for (int i = tid; i < NB; i += 256) { bas[i] = mat[i * PBLK + blk]; cur[i] = 0; }
    __syncthreads();
    int base = blk * ECH;
    for (int k = tid; k < ECH; k += 256) {
        int e = base + k;
        int r = ei[e];
        int c = ei[NE + e];
        int b = c >> 8;
        int local = atomicAdd(&cur[b], 1);
        part[bas[b] + local] = (unsigned)r | ((unsigned)(c & 255) << 24);
    }
}

__global__ void bucket_build(const unsigned int* __restrict__ part, const int* __restrict__ mat,
                             const float* __restrict__ x, int* __restrict__ csr_row,
                             int* __restrict__ ideg, int* __restrict__ offs,
                             float* __restrict__ dinv, float4* __restrict__ xpad,
                             uint4* __restrict__ xs) {
    __shared__ int lh[256];
    __shared__ int lex[256];
    __shared__ int cur[256];
    int b = blockIdx.x, tid = threadIdx.x;
    int ebase = mat[b * PBLK];
    int eend = (b == NB - 1) ? NE : mat[(b + 1) * PBLK];
    int m = eend - ebase;
    lh[tid] = 0;
    __syncthreads();
    for (int k = tid; k < m; k += 256) {
        unsigned v = part[ebase + k];
        atomicAdd(&lh[v >> 24], 1);
    }
    __syncthreads();
    int cnt = lh[tid];
    lex[tid] = cnt;
    __syncthreads();
    for (int off = 1; off < 256; off <<= 1) {
        int v = (tid >= off) ? lex[tid - off] : 0;
        __syncthreads();
        lex[tid] += v;
        __syncthreads();
    }
    int excl = lex[tid] - cnt;
    lex[tid] = excl;
    cur[tid] = 0;
    int n = b * 256 + tid;
    if (n < NN) {
        ideg[n] = cnt;
        offs[n] = ebase + excl;
        float di = rsqrtf((float)cnt + 1.0f);
        dinv[n] = di;
        float x0 = x[n * 3], x1 = x[n * 3 + 1], x2 = x[n * 3 + 2];
        xpad[n] = make_float4(x0, x1, x2, di);
        _Float16 hx = (_Float16)x0, hy = (_Float16)x1, hz = (_Float16)x2;
        half2v sx = {hx, hx}, sy = {hy, hy}, sz = {hz, hz};
        xs[n] = make_uint4(__builtin_bit_cast(unsigned int, sx),
                           __builtin_bit_cast(unsigned int, sy),
                           __builtin_bit_cast(unsigned int, sz), 0u);
    }
    if (b == 0 && tid == 0) offs[NN] = NE;
    __syncthreads();
    for (int k = tid; k < m; k += 256) {
        unsigned v = part[ebase + k];
        int cl = (int)(v >> 24);
        int r = (int)(v & 0x00FFFFFFu);
        int local = atomicAdd(&cur[cl], 1);
        csr_row[ebase + lex[cl] + local] = r;
    }
}

// Materialize source-node coord splats in CSR edge order (planar dwords).
// Edge-parallel independent gathers (xs is L2-resident) -> latency fully
// hidden by TLP; removes the dependent csr->xs hop from edgeconv.
__global__ void csr_gather(const int* __restrict__ csr_row, const uint4* __restrict__ xs,
                           unsigned* __restrict__ csx, unsigned* __restrict__ csy,
                           unsigned* __restrict__ csz) {
    int e = blockIdx.x * 256 + threadIdx.x;
    if (e >= NE) return;
    int r = csr_row[e];
    uint4 u = xs[r];
    csx[e] = u.x;
    csy[e] = u.y;
    csz[e] = u.z;
}

// ---- edgeconv helpers: round-3 math (bit-identical order) ----
#define EC_PAIR(QQ, SRC) do { \
    half2v px_ = bch(__shfl((int)(QQ).x, (SRC), 64)); \
    half2v py_ = bch(__shfl((int)(QQ).y, (SRC), 64)); \
    half2v pz_ = bch(__shfl((int)(QQ).z, (SRC), 64)); \
    _Pragma("unroll") \
    for (int p = 0; p < 5; ++p) { \
        half2v v = va[p] + px_ * A0[p] + py_ * A1[p] + pz_ * A2[p]; \
        v = __builtin_elementwise_max(v, zero); \
        acc[p] += v; \
    } } while (0)

#define EC_FLUSH() do { \
    _Pragma("unroll") \
    for (int p = 0; p < 5; ++p) { \
        accf[2 * p]     += (float)acc[p].x; \
        accf[2 * p + 1] += (float)acc[p].y; \
        acc[p] = zero; \
    } } while (0)

#define EC_CHUNK_FROM(T0, QQ, C2) do { \
    int tfull_ = (C2) >> 1; \
    int t_ = (T0); \
    for (; t_ + 4 <= tfull_; t_ += 4) { \
        _Pragma("unroll") \
        for (int u = 0; u < 4; ++u) EC_PAIR(QQ, 2 * (t_ + u) + half); \
        EC_FLUSH(); \
    } \
    for (; t_ < tfull_; ++t_) EC_PAIR(QQ, 2 * t_ + half); \
    if ((C2) & 1) { \
        int src_ = (C2) - 1; \
        half2v px_ = bch(__shfl((int)(QQ).x, src_, 64)); \
        half2v py_ = bch(__shfl((int)(QQ).y, src_, 64)); \
        half2v pz_ = bch(__shfl((int)(QQ).z, src_, 64)); \
        if (half == 0) { \
            _Pragma("unroll") \
            for (int p = 0; p < 5; ++p) { \
                half2v v = va[p] + px_ * A0[p] + py_ * A1[p] + pz_ * A2[p]; \
                v = __builtin_elementwise_max(v, zero); \
                acc[p] += v; \
            } \
        } \
    } \
    EC_FLUSH(); } while (0)

#define EC_LOADQ(DST, EE, LIM) do { \
    bool ok_ = (EE) < (LIM); \
    (DST).x = ok_ ? csx[(EE)] : 0u; \
    (DST).y = ok_ ? csy[(EE)] : 0u; \
    (DST).z = ok_ ? csz[(EE)] : 0u; \
} while (0)

// Edge phase, packed fp16. Chunk coords now come from the planar CSR-ordered
// splat arrays -> coalesced loads, no dependent gather; all of next node's
// loads issue at iteration top (dependency only on offs, prefetched 2 ahead).
__global__ __launch_bounds__(256, 4) void edgeconv_fused(
    const uint4* __restrict__ xs, const int* __restrict__ offs,
    const unsigned* __restrict__ csx, const unsigned* __restrict__ csy,
    const unsigned* __restrict__ csz, const float* __restrict__ tab,
    _Float16* __restrict__ aggh) {
    int lane = threadIdx.x & 63;
    int j = lane & 31;
    int half = lane >> 5;

    half2v A0[5], A1[5], A2[5], B0[5], B1[5], B2[5], hb[5];
#pragma unroll
    for (int p = 0; p < 5; ++p) {
        int c0 = 2 * p, c1 = 2 * p + 1;
        A0[p] = half2v{(_Float16)tab[c0 * 96 + j],        (_Float16)tab[c1 * 96 + j]};
        A1[p] = half2v{(_Float16)tab[c0 * 96 + 32 + j],   (_Float16)tab[c1 * 96 + 32 + j]};
        A2[p] = half2v{(_Float16)tab[c0 * 96 + 64 + j],   (_Float16)tab[c1 * 96 + 64 + j]};
        B0[p] = half2v{(_Float16)tab[960 + c0 * 96 + j],      (_Float16)tab[960 + c1 * 96 + j]};
        B1[p] = half2v{(_Float16)tab[960 + c0 * 96 + 32 + j], (_Float16)tab[960 + c1 * 96 + 32 + j]};
        B2[p] = half2v{(_Float16)tab[960 + c0 * 96 + 64 + j], (_Float16)tab[960 + c1 * 96 + 64 + j]};
        hb[p] = half2v{(_Float16)tab[1920 + c0 * 32 + j], (_Float16)tab[1920 + c1 * 32 + j]};
    }
    const half2v zero = half2v{(_Float16)0.f, (_Float16)0.f};

    int wid = blockIdx.x * 4 + (threadIdx.x >> 6);
    const int ws = gridDim.x * 4;

    int n = wid;
    if (n >= NN) return;
    int e0 = offs[n];
    int e1 = offs[n + 1];
    uint4 qn = xs[n];
    int n2 = n + ws;
    int e0n = 0, e1n = 0;
    if (n2 < NN) { e0n = offs[n2]; e1n = offs[n2 + 1]; }
    uint4 q;
    EC_LOADQ(q, e0 + lane, e1);

    while (true) {
        int n3 = n2 + ws;
        int e0n2 = 0, e1n2 = 0;
        if (n3 < NN) { e0n2 = offs[n3]; e1n2 = offs[n3 + 1]; }
        uint4 qn2 = make_uint4(0u, 0u, 0u, 0u);
        if (n2 < NN) qn2 = xs[n2];

        // issue next chunk's loads now (this node's 2nd chunk, or next node's 1st)
        bool multi = (e1 - e0) > 64;
        int pb = multi ? (e0 + 64) : e0n;
        int pe = multi ? e1 : e1n;
        uint4 qpre;
        EC_LOADQ(qpre, pb + lane, pe);

        half2v pxn = bch((int)qn.x), pyn = bch((int)qn.y), pzn = bch((int)qn.z);
        half2v va[5], acc[5];
        float accf[10];
#pragma unroll
        for (int p = 0; p < 5; ++p) {
            va[p] = hb[p] + pxn * B0[p] + pyn * B1[p] + pzn * B2[p];
            acc[p] = zero;
            accf[2 * p] = 0.f;
            accf[2 * p + 1] = 0.f;
        }

        int c2 = e1 - e0;
        if (c2 > 64) c2 = 64;
        EC_CHUNK_FROM(0, q, c2);

        if (multi) {
            int base = e0 + 64;
            uint4 qc = qpre;
            while (true) {
                int cc = e1 - base;
                if (cc > 64) cc = 64;
                int nb = base + 64;
                bool m2 = nb < e1;
                int pb2 = m2 ? nb : e0n;
                int pe2 = m2 ? e1 : e1n;
                uint4 qp2;
                EC_LOADQ(qp2, pb2 + lane, pe2);
                EC_CHUNK_FROM(0, qc, cc);
                qc = qp2;
                if (!m2) break;
                base = nb;
            }
            qpre = qc;
        }

        // cross-half reduce: all lanes end with full accf[0..9]
#pragma unroll
        for (int c = 0; c < 10; ++c) accf[c] += __shfl_xor(accf[c], 32, 64);
        // packed contiguous row store (K-permuted layout): dword d = p*32 + jch,
        // lanes cover d = i*64 + lane for i=0,1 and d = 128 + lane (half0).
        unsigned* arow32 = (unsigned*)(aggh + (size_t)n * 320);
        half2v d0 = {(_Float16)accf[2 * half],     (_Float16)accf[2 * half + 1]};
        half2v d1 = {(_Float16)accf[4 + 2 * half], (_Float16)accf[4 + 2 * half + 1]};
        arow32[lane]      = __builtin_bit_cast(unsigned, d0);
        arow32[64 + lane] = __builtin_bit_cast(unsigned, d1);
        if (half == 0) {
            half2v d2 = {(_Float16)accf[8], (_Float16)accf[9]};
            arow32[128 + lane] = __builtin_bit_cast(unsigned, d2);
        }

        if (n2 >= NN) return;
        n = n2;
        n2 = n3;
        e0 = e0n; e1 = e1n;
        e0n = e0n2; e1n = e1n2;
        qn = qn2;
        q = qpre;
    }
}

// Fold via MFMA (plain fp16, 2 MFMA/kc) + fused xw1-init; writes y1 = h*dinv fp16.
__global__ __launch_bounds__(256) void fold_mfma(
    const _Float16* __restrict__ aggh, const _Float16* __restrict__ MfragG,
    const float4* __restrict__ xpad, const int* __restrict__ ideg,
    const float* __restrict__ tab, const float* __restrict__ g1W,
    _Float16* __restrict__ y1) {
    __shared__ _Float16 Mf[10240];
    {
        const uint4* src = (const uint4*)MfragG;
        uint4* dst = (uint4*)Mf;
        for (int i = threadIdx.x; i < 1280; i += 256) dst[i] = src[i];
    }
    __syncthreads();

    int wave = blockIdx.x * 4 + (threadIdx.x >> 6);
    int lane = threadIdx.x & 63;
    int n0 = wave * 16;
    if (n0 >= NN) return;

    int m = lane & 15, q = lane >> 4;
    int arow_n = n0 + m;
    bool rowok = arow_n < NN;
    const _Float16* arow = aggh + (size_t)arow_n * 320 + q * 8;

    const half8* mf = (const half8*)Mf;
    f32x4 acc0 = {0.f, 0.f, 0.f, 0.f};
    f32x4 acc1 = {0.f, 0.f, 0.f, 0.f};

    for (int kc = 0; kc < 10; ++kc) {
        half8 a;
        if (rowok) a = *(const half8*)(arow + kc * 32);
        else {
#pragma unroll
            for (int i = 0; i < 8; ++i) a[i] = (_Float16)0.f;
        }
        half8 b0 = mf[(kc * 2 + 0) * 64 + lane];
        half8 b1 = mf[(kc * 2 + 1) * 64 + lane];
        acc0 = __builtin_amdgcn_mfma_f32_16x16x32_f16(a, b0, acc0, 0, 0, 0);
        acc1 = __builtin_amdgcn_mfma_f32_16x16x32_f16(a, b1, acc1, 0, 0, 0);
    }

    int jcol = lane & 15;
    float t0 = tab[12480 + jcol],      t1 = tab[12480 + 16 + jcol];
    float w00 = g1W[jcol],      w01 = g1W[32 + jcol],      w02 = g1W[64 + jcol];
    float w10 = g1W[16 + jcol], w11 = g1W[48 + jcol],      w12 = g1W[80 + jcol];
#pragma unroll
    for (int r = 0; r < 4; ++r) {
        int node = n0 + q * 4 + r;
        if (node < NN) {
            float4 xn = xpad[node];
            float dg = (float)ideg[node];
            float v0 = dg * t0 + xn.x * w00 + xn.y * w01 + xn.z * w02 + acc0[r];
            float v1 = dg * t1 + xn.x * w10 + xn.y * w11 + xn.z * w12 + acc1[r];
            y1[node * 32 + jcol]      = (_Float16)(v0 * xn.w);
            y1[node * 32 + 16 + jcol] = (_Float16)(v1 * xn.w);
        }
    }
}

// prop1 + fused xw2: 4 nodes/wave, 16 lanes/node, double-buffered gather groups.
__global__ __launch_bounds__(256, 8) void prop1_fused(
    const int* __restrict__ offs, const int* __restrict__ csr_row,
    const unsigned int* __restrict__ y1p, const float* __restrict__ dinv,
    const float* __restrict__ g1b, const float* __restrict__ g2W,
    unsigned int* __restrict__ y2p) {
    __shared__ float g2s[1024];
    for (int i = threadIdx.x; i < 1024; i += 256) g2s[i] = g2W[i];
    __syncthreads();

    int lane = threadIdx.x & 63;
    int l = lane & 15;
    int wid = blockIdx.x * 4 + (threadIdx.x >> 6);
    int n = wid * 4 + (lane >> 4);
    if (n >= NN) return;

    int e0 = offs[n], e1 = offs[n + 1];
    float di = dinv[n];
    half2v pn = __builtin_bit_cast(half2v, y1p[n * 16 + l]);
    float sAl = 0.f, sAh = 0.f, sBl = 0.f, sBh = 0.f;
    int e = e0;
    if (e + 7 < e1) {
        half2v p0[8];
        {
            int r0[8];
#pragma unroll
            for (int u = 0; u < 8; ++u) r0[u] = csr_row[e + u];
#pragma unroll
            for (int u = 0; u < 8; ++u) p0[u] = __builtin_bit_cast(half2v, y1p[r0[u] * 16 + l]);
        }
        while (true) {
            int e2 = e + 8;
            bool more = (e2 + 7 < e1);
            half2v p1[8];
            if (more) {
                int r1[8];
#pragma unroll
                for (int u = 0; u < 8; ++u) r1[u] = csr_row[e2 + u];
#pragma unroll
                for (int u = 0; u < 8; ++u) p1[u] = __builtin_bit_cast(half2v, y1p[r1[u] * 16 + l]);
            }
#pragma unroll
            for (int u = 0; u < 8; u += 2) {
                sAl += (float)p0[u].x;     sAh += (float)p0[u].y;
                sBl += (float)p0[u + 1].x; sBh += (float)p0[u + 1].y;
            }
            e = e2;
            if (!more) break;
#pragma unroll
            for (int u = 0; u < 8; ++u) p0[u] = p1[u];
        }
    }
    if (e + 3 < e1) {
        int r[4];
#pragma unroll
        for (int u = 0; u < 4; ++u) r[u] = csr_row[e + u];
        half2v p[4];
#pragma unroll
        for (int u = 0; u < 4; ++u) p[u] = __builtin_bit_cast(half2v, y1p[r[u] * 16 + l]);
        sAl += (float)p[0].x + (float)p[2].x; sAh += (float)p[0].y + (float)p[2].y;
        sBl += (float)p[1].x + (float)p[3].x; sBh += (float)p[1].y + (float)p[3].y;
        e += 4;
    }
    if (e + 1 < e1) {
        int r0 = csr_row[e], r1 = csr_row[e + 1];
        half2v p0 = __builtin_bit_cast(half2v, y1p[r0 * 16 + l]);
        half2v p1 = __builtin_bit_cast(half2v, y1p[r1 * 16 + l]);
        sAl += (float)p0.x; sAh += (float)p0.y;
        sBl += (float)p1.x; sBh += (float)p1.y;
        e += 2;
    }
    if (e < e1) {
        int r = csr_row[e];
        half2v p = __builtin_bit_cast(half2v, y1p[r * 16 + l]);
        sAl += (float)p.x; sAh += (float)p.y;
    }
    float h1l = di * (sAl + sBl + (float)pn.x);
    float h1h = di * (sAh + sBh + (float)pn.y);
    float hl = fmaxf(h1l + g1b[2 * l], 0.f);
    float hh = fmaxf(h1h + g1b[2 * l + 1], 0.f);

    float al = 0.f, ah = 0.f;
    int base = lane & 48;
#pragma unroll
    for (int m = 0; m < 16; ++m) {
        float xl = __shfl(hl, base + m, 64);
        float xh2 = __shfl(hh, base + m, 64);
        al += xl * g2s[(2 * m) * 32 + 2 * l] + xh2 * g2s[(2 * m + 1) * 32 + 2 * l];
        ah += xl * g2s[(2 * m) * 32 + 2 * l + 1] + xh2 * g2s[(2 * m + 1) * 32 + 2 * l + 1];
    }
    half2v o = {(_Float16)(al * di), (_Float16)(ah * di)};
    y2p[n * 16 + l] = __builtin_bit_cast(unsigned int, o);
}

// prop2 slot layout: 1 node/wave, lane = (edge-slot 0..3, channel 0..15).
__global__ __launch_bounds__(256, 8) void prop2_slot(
    const int* __restrict__ offs, const int* __restrict__ csr_row,
    const unsigned int* __restrict__ y2p, const float* __restrict__ dinv,
    unsigned int* __restrict__ outp) {
    int lane = threadIdx.x & 63;
    int l = lane & 15;
    int slot = lane >> 4;
    int n = blockIdx.x * 4 + (threadIdx.x >> 6);
    if (n >= NN) return;

    int e0 = offs[n], e1 = offs[n + 1];
    float di = dinv[n];
    half2v pn = __builtin_bit_cast(half2v, y2p[n * 16 + l]);
    float sl = 0.f, sh = 0.f;
    int e = e0;
    if (e < e1) {
        int i0 = e + slot, i1 = e + 4 + slot;
        int rA = csr_row[(i0 < e1) ? i0 : (e1 - 1)];
        int rB = csr_row[(i1 < e1) ? i1 : (e1 - 1)];
        bool okA = i0 < e1, okB = i1 < e1;
        while (true) {
            half2v pA = __builtin_bit_cast(half2v, y2p[rA * 16 + l]);
            half2v pB = __builtin_bit_cast(half2v, y2p[rB * 16 + l]);
            int en = e + 8;
            bool more = en < e1;
            int rA2 = 0, rB2 = 0;
            bool okA2 = false, okB2 = false;
            if (more) {
                int j0 = en + slot, j1 = en + 4 + slot;
                rA2 = csr_row[(j0 < e1) ? j0 : (e1 - 1)];
                rB2 = csr_row[(j1 < e1) ? j1 : (e1 - 1)];
                okA2 = j0 < e1; okB2 = j1 < e1;
            }
            if (okA) { sl += (float)pA.x; sh += (float)pA.y; }
            if (okB) { sl += (float)pB.x; sh += (float)pB.y; }
            e = en;
            if (!more) break;
            rA = rA2; rB = rB2; okA = okA2; okB = okB2;
        }
    }
    sl += __shfl_xor(sl, 16, 64); sl += __shfl_xor(sl, 32, 64);
    sh += __shfl_xor(sh, 16, 64); sh += __shfl_xor(sh, 32, 64);
    if (slot == 0) {
        half2v o = {(_Float16)(di * (sl + (float)pn.x)),
                    (_Float16)(di * (sh + (float)pn.y))};
        outp[n * 16 + l] = __builtin_bit_cast(unsigned int, o);
    }
}

__global__ void pool_seg(const _Float16* __restrict__ h2, const float* __restrict__ g2b,
                         const int* __restrict__ batch, float* __restrict__ pooled,
                         float* __restrict__ counts) {
    int grp = threadIdx.x >> 5, j = threadIdx.x & 31;
    int base = (blockIdx.x * 8 + grp) * 64;
    if (base >= NN) return;
    float bj = g2b[j];
    float acc = 0.f, cnt = 0.f;
    int curg = -1;
    int lim = base + 64;
    if (lim > NN) lim = NN;
    for (int n = base; n < lim; ++n) {
        int g = batch[n];
        if (g != curg) {
            if (curg >= 0) {
                atomicAdd(&pooled[curg * 32 + j], acc);
                if (j == 0) atomicAdd(&counts[curg], cnt);
            }
            curg = g; acc = 0.f; cnt = 0.f;
        }
        acc += fmaxf((float)h2[n * 32 + j] + bj, 0.f);
        cnt += 1.f;
    }
    if (curg >= 0) {
        atomicAdd(&pooled[curg * 32 + j], acc);
        if (j == 0) atomicAdd(&counts[curg], cnt);
    }
}

__global__ void final_kernel(const float* __restrict__ pooled, const float* __restrict__ counts,
                             const float* __restrict__ clsW, const float* __restrict__ clsb,
                             float* __restrict__ out) {
    int tid = threadIdx.x;
    if (tid >= GG * CC) return;
    int g = tid / CC, cc = tid % CC;
    float inv = 1.0f / fmaxf(counts[g], 1.0f);
    float s = clsb[cc];
    for (int j = 0; j < 32; ++j) s += (pooled[g * 32 + j] * inv) * clsW[j * CC + cc];
    out[g * CC + cc] = s;
}

extern "C" void kernel_launch(void* const* d_in, const int* in_sizes, int n_in,
                              void* d_out, int out_size, void* d_ws, size_t ws_size,
                              hipStream_t stream) {
    const float* x     = (const float*)d_in[0];
    const int*   ei    = (const int*)d_in[1];
    const int*   batch = (const int*)d_in[2];
    const float* fW    = (const float*)d_in[3];
    const float* fb    = (const float*)d_in[4];
    const float* W1    = (const float*)d_in[5];
    const float* b1    = (const float*)d_in[6];
    const float* W2    = (const float*)d_in[7];
    const float* b2    = (const float*)d_in[8];
    const float* g1W   = (const float*)d_in[9];
    const float* g1b   = (const float*)d_in[10];
    const float* g2W   = (const float*)d_in[11];
    const float* g2b   = (const float*)d_in[12];
    const float* clsW  = (const float*)d_in[13];
    const float* clsb  = (const float*)d_in[14];
    float* out = (float*)d_out;

    float4*         xpad    = (float4*)d_ws;                          // 1.6 MB
    uint4*          xs      = (uint4*)(xpad + NN);                    // 1.6 MB (fp16 splats)
    _Float16*       aggh    = (_Float16*)(xs + NN);                   // 64 MB
    unsigned int*   part    = (unsigned int*)aggh;                    // ALIAS: build-phase only
    int*            csr_row = (int*)(aggh + (size_t)NN * 320);        // 6.4 MB
    int*            mat     = (int*)(csr_row + NE);
    int*            msum    = mat + MTOT;
    int*            ideg    = msum + 256;
    int*            offs    = ideg + NN;
    float*          dinv    = (float*)(offs + NN + 1);
    float*          tab     = dinv + NN;
    _Float16*       Mfrag   = (_Float16*)(tab + 16384);               // 20 KB
    _Float16*       y1      = Mfrag + 10240;                          // 6.4 MB
    unsigned int*   y2p     = (unsigned int*)(y1 + (size_t)NN * 32);  // 6.4 MB
    unsigned int*   h2p     = y2p + (size_t)NN * 16;                  // 6.4 MB
    float*          pooled  = (float*)(h2p + (size_t)NN * 16);
    float*          counts  = pooled + GG * 32;
    // csx/csy/csz alias the y1/y2/h2 run (19.2 MB): used only between
    // csr_gather and edgeconv; y1 is first written by fold_mfma (after).
    unsigned int*   csx     = (unsigned int*)y1;
    unsigned int*   csy     = csx + NE;
    unsigned int*   csz     = csy + NE;

    const int propBlocks = (NN + 15) / 16;
    const int foldBlocks = ((NN + 15) / 16 + 3) / 4;
    const int slotBlocks = (NN + 3) / 4;
    const int edgeBlocks = (NE + 255) / 256;

    precompute_small<<<10, 1024, 0, stream>>>(fW, fb, W1, b1, W2, b2, g1W, tab, Mfrag);

    bucket_hist<<<PBLK, 256, 0, stream>>>(ei, mat);
    scan_m1<<<MSB, 256, 0, stream>>>(mat, msum);
    scan_m2<<<1, 256, 0, stream>>>(msum, pooled);
    scan_m3<<<MSB, 256, 0, stream>>>(mat, msum);
    bucket_scatter<<<PBLK, 256, 0, stream>>>(ei, mat, part);
    bucket_build<<<NB, 256, 0, stream>>>(part, mat, x, csr_row, ideg, offs, dinv, xpad, xs);
    csr_gather<<<edgeBlocks, 256, 0, stream>>>(csr_row, xs, csx, csy, csz);

    edgeconv_fused<<<2048, 256, 0, stream>>>(xs, offs, csx, csy, csz, tab, aggh);
    fold_mfma<<<foldBlocks, 256, 0, stream>>>(aggh, Mfrag, xpad, ideg, tab, g1W, y1);

    prop1_fused<<<propBlocks, 256, 0, stream>>>(offs, csr_row, (const unsigned int*)y1,
                                                dinv, g1b, g2W, y2p);
    prop2_slot<<<slotBlocks, 256, 0, stream>>>(offs, csr_row, y2p, dinv, h2p);
    pool_seg<<<(NN + 511) / 512, 256, 0, stream>>>((const _Float16*)h2p, g2b, batch,
                                                   pooled, counts);
    final_kernel<<<1, 640, 0, stream>>>(pooled, counts, clsW, clsb, out);
}

// Round 12
// 357.360 us; speedup vs baseline: 1.0328x; 1.0328x over previous
//
#include <hip/hip_runtime.h>

#define NN 100000
#define NE 1600000
#define HH 32
#define CC 10
#define GG 64
#define NB 391
#define PBLK 160
#define ECH 10000
#define MTOT (NB * PBLK)
#define MSB ((MTOT + 255) / 256)

typedef _Float16 half8 __attribute__((ext_vector_type(8)));
typedef _Float16 half2v __attribute__((ext_vector_type(2)));
typedef float f32x4 __attribute__((ext_vector_type(4)));

__device__ __forceinline__ half2v bch(int v) { return __builtin_bit_cast(half2v, v); }

// K-permutation shared by edgeconv stores, Mfrag build, and fold_mfma:
// knew = p*64 + jch*2 + s  <->  korig = (2p+s)*32 + jch   (class = 2p+s, channel = jch)
// MFMA sums over K, so any consistent permutation is exact.

__global__ void precompute_small(const float* __restrict__ fW, const float* __restrict__ fb,
                                 const float* __restrict__ W1, const float* __restrict__ b1,
                                 const float* __restrict__ W2, const float* __restrict__ b2,
                                 const float* __restrict__ g1W, float* __restrict__ tab,
                                 _Float16* __restrict__ Mfrag) {
    int c = blockIdx.x;
    int k = threadIdx.x >> 5;
    int j = threadIdx.x & 31;
    float m = 0.f;
    for (int mm = 0; mm < 32; ++mm)
        m += W2[k * 32 + mm] * g1W[(3 + 32 * c + mm) * 32 + j];
    tab[2240 + c * 1024 + k * 32 + j] = m;

    if (k < 3) {
        float a = 0.f, b = 0.f;
        for (int i = 0; i < 32; ++i) {
            float w = fW[c * 96 + k * 32 + i];
            a += w * W1[i * 32 + j];
            b += w * W1[(32 + i) * 32 + j];
        }
        tab[c * 96 + k * 32 + j] = a;
        tab[960 + c * 96 + k * 32 + j] = b;
    } else if (k == 3) {
        float h = b1[j];
        for (int i = 0; i < 32; ++i)
            h += fb[c * 32 + i] * (W1[i * 32 + j] + W1[(32 + i) * 32 + j]);
        tab[1920 + c * 32 + j] = h;
    } else if (k == 4 && c == 0) {
        float t = 0.f;
        for (int cc2 = 0; cc2 < CC; ++cc2)
            for (int mm = 0; mm < 32; ++mm)
                t += b2[mm] * g1W[(3 + 32 * cc2 + mm) * 32 + j];
        tab[12480 + j] = t;
    }
    __syncthreads();
    // Mfrag entries whose K-row belongs to class c (this block computed those rows above).
    {
        int jch = k;
        int jcol = j;
        float v = tab[2240 + c * 1024 + jch * 32 + jcol];
        int knew = (c >> 1) * 64 + 2 * jch + (c & 1);
        int kc = knew >> 5, within = knew & 31;
        int jt = jcol >> 4;
        int lq = within >> 3, ii = within & 7;
        int lidx = lq * 16 + (jcol & 15);
        int flat = ((kc * 2 + jt) * 64 + lidx) * 8 + ii;
        Mfrag[flat] = (_Float16)v;
    }
}

// ---- atomic-free CSR build (bucket two-phase: scatter locality, r8 lesson) ----
__global__ void bucket_hist(const int* __restrict__ ei, int* __restrict__ mat) {
    __shared__ int h[NB];
    int blk = blockIdx.x, tid = threadIdx.x;
    for (int i = tid; i < NB; i += 256) h[i] = 0;
    __syncthreads();
    int base = blk * ECH;
    for (int k = tid; k < ECH; k += 256)
        atomicAdd(&h[ei[NE + base + k] >> 8], 1);
    __syncthreads();
    for (int i = tid; i < NB; i += 256) mat[i * PBLK + blk] = h[i];
}

__global__ void scan_m1(const int* __restrict__ mat, int* __restrict__ msum) {
    __shared__ int sh[256];
    int b = blockIdx.x, t = threadIdx.x;
    int i = b * 256 + t;
    sh[t] = (i < MTOT) ? mat[i] : 0;
    __syncthreads();
    for (int off = 128; off > 0; off >>= 1) {
        if (t < off) sh[t] += sh[t + off];
        __syncthreads();
    }
    if (t == 0) msum[b] = sh[0];
}

__global__ void scan_m2(int* __restrict__ msum, float* __restrict__ pooled) {
    // also zero pooled+counts (GG*33 floats) -- absorbed zero_f kernel
    for (int i = threadIdx.x; i < GG * 33; i += 256) pooled[i] = 0.0f;
    __shared__ int sh[256];
    int t = threadIdx.x;
    int v = (t < MSB) ? msum[t] : 0;
    sh[t] = v;
    __syncthreads();
    for (int off = 1; off < 256; off <<= 1) {
        int add = (t >= off) ? sh[t - off] : 0;
        __syncthreads();
        sh[t] += add;
        __syncthreads();
    }
    if (t < MSB) msum[t] = sh[t] - v;
}

__global__ void scan_m3(int* __restrict__ mat, const int* __restrict__ msum) {
    __shared__ int sh[256];
    int b = blockIdx.x, t = threadIdx.x;
    int i = b * 256 + t;
    int v = (i < MTOT) ? mat[i] : 0;
    sh[t] = v;
    __syncthreads();
    for (int off = 1; off < 256; off <<= 1) {
        int add = (t >= off) ? sh[t - off] : 0;
        __syncthreads();
        sh[t] += add;
        __syncthreads();
    }
    if (i < MTOT) mat[i] = sh[t] - v + msum[b];
}

__global__ void bucket_scatter(const int* __restrict__ ei, const int* __restrict__ mat,
                               unsigned int* __restrict__ part) {
    __shared__ int bas[NB];
    __shared__ int cur[NB];
    int blk = blockIdx.x, tid = threadIdx.x;
    for (int i = tid; i < NB; i += 256) { bas[i] = mat[i * PBLK + blk]; cur[i] = 0; }
    __syncthreads();
    int base = blk * ECH;
    for (int k = tid; k < ECH; k += 256) {
        int e = base + k;
        int r = ei[e];
        int c = ei[NE + e];
        int b = c >> 8;
        int local = atomicAdd(&cur[b], 1);
        part[bas[b] + local] = (unsigned)r | ((unsigned)(c & 255) << 24);
    }
}

__global__ void bucket_build(const unsigned int* __restrict__ part, const int* __restrict__ mat,
                             const float* __restrict__ x, int* __restrict__ csr_row,
                             int* __restrict__ ideg, int* __restrict__ offs,
                             float* __restrict__ dinv, float4* __restrict__ xpad,
                             uint4* __restrict__ xs) {
    __shared__ int lh[256];
    __shared__ int lex[256];
    __shared__ int cur[256];
    int b = blockIdx.x, tid = threadIdx.x;
    int ebase = mat[b * PBLK];
    int eend = (b == NB - 1) ? NE : mat[(b + 1) * PBLK];
    int m = eend - ebase;
    lh[tid] = 0;
    __syncthreads();
    for (int k = tid; k < m; k += 256) {
        unsigned v = part[ebase + k];
        atomicAdd(&lh[v >> 24], 1);
    }
    __syncthreads();
    int cnt = lh[tid];
    lex[tid] = cnt;
    __syncthreads();
    for (int off = 1; off < 256; off <<= 1) {
        int v = (tid >= off) ? lex[tid - off] : 0;
        __syncthreads();
        lex[tid] += v;
        __syncthreads();
    }
    int excl = lex[tid] - cnt;
    lex[tid] = excl;
    cur[tid] = 0;
    int n = b * 256 + tid;
    if (n < NN) {
        ideg[n] = cnt;
        offs[n] = ebase + excl;
        float di = rsqrtf((float)cnt + 1.0f);
        dinv[n] = di;
        float x0 = x[n * 3], x1 = x[n * 3 + 1], x2 = x[n * 3 + 2];
        xpad[n] = make_float4(x0, x1, x2, di);
        _Float16 hx = (_Float16)x0, hy = (_Float16)x1, hz = (_Float16)x2;
        half2v sx = {hx, hx}, sy = {hy, hy}, sz = {hz, hz};
        xs[n] = make_uint4(__builtin_bit_cast(unsigned int, sx),
                           __builtin_bit_cast(unsigned int, sy),
                           __builtin_bit_cast(unsigned int, sz), 0u);
    }
    if (b == 0 && tid == 0) offs[NN] = NE;
    __syncthreads();
    for (int k = tid; k < m; k += 256) {
        unsigned v = part[ebase + k];
        int cl = (int)(v >> 24);
        int r = (int)(v & 0x00FFFFFFu);
        int local = atomicAdd(&cur[cl], 1);
        csr_row[ebase + lex[cl] + local] = r;
    }
}

// ---- edgeconv helpers: round-3 form (best measured) ----
#define EC_PAIR(QQ, SRC) do { \
    half2v px_ = bch(__shfl((int)(QQ).x, (SRC), 64)); \
    half2v py_ = bch(__shfl((int)(QQ).y, (SRC), 64)); \
    half2v pz_ = bch(__shfl((int)(QQ).z, (SRC), 64)); \
    _Pragma("unroll") \
    for (int p = 0; p < 5; ++p) { \
        half2v v = va[p] + px_ * A0[p] + py_ * A1[p] + pz_ * A2[p]; \
        v = __builtin_elementwise_max(v, zero); \
        acc[p] += v; \
    } } while (0)

#define EC_FLUSH() do { \
    _Pragma("unroll") \
    for (int p = 0; p < 5; ++p) { \
        accf[2 * p]     += (float)acc[p].x; \
        accf[2 * p + 1] += (float)acc[p].y; \
        acc[p] = zero; \
    } } while (0)

#define EC_CHUNK_FROM(T0, QQ, C2) do { \
    int tfull_ = (C2) >> 1; \
    int t_ = (T0); \
    for (; t_ + 4 <= tfull_; t_ += 4) { \
        _Pragma("unroll") \
        for (int u = 0; u < 4; ++u) EC_PAIR(QQ, 2 * (t_ + u) + half); \
        EC_FLUSH(); \
    } \
    for (; t_ < tfull_; ++t_) EC_PAIR(QQ, 2 * t_ + half); \
    if ((C2) & 1) { \
        int src_ = (C2) - 1; \
        half2v px_ = bch(__shfl((int)(QQ).x, src_, 64)); \
        half2v py_ = bch(__shfl((int)(QQ).y, src_, 64)); \
        half2v pz_ = bch(__shfl((int)(QQ).z, src_, 64)); \
        if (half == 0) { \
            _Pragma("unroll") \
            for (int p = 0; p < 5; ++p) { \
                half2v v = va[p] + px_ * A0[p] + py_ * A1[p] + pz_ * A2[p]; \
                v = __builtin_elementwise_max(v, zero); \
                acc[p] += v; \
            } \
        } \
    } \
    EC_FLUSH(); } while (0)

// Edge phase, packed fp16, software-pipelined (round-3 form; best measured).
__global__ __launch_bounds__(256, 4) void edgeconv_fused(
    const uint4* __restrict__ xs, const int* __restrict__ offs,
    const int* __restrict__ csr_row, const float* __restrict__ tab,
    _Float16* __restrict__ aggh) {
    int lane = threadIdx.x & 63;
    int j = lane & 31;
    int half = lane >> 5;

    half2v A0[5], A1[5], A2[5], B0[5], B1[5], B2[5], hb[5];
#pragma unroll
    for (int p = 0; p < 5; ++p) {
        int c0 = 2 * p, c1 = 2 * p + 1;
        A0[p] = half2v{(_Float16)tab[c0 * 96 + j],        (_Float16)tab[c1 * 96 + j]};
        A1[p] = half2v{(_Float16)tab[c0 * 96 + 32 + j],   (_Float16)tab[c1 * 96 + 32 + j]};
        A2[p] = half2v{(_Float16)tab[c0 * 96 + 64 + j],   (_Float16)tab[c1 * 96 + 64 + j]};
        B0[p] = half2v{(_Float16)tab[960 + c0 * 96 + j],      (_Float16)tab[960 + c1 * 96 + j]};
        B1[p] = half2v{(_Float16)tab[960 + c0 * 96 + 32 + j], (_Float16)tab[960 + c1 * 96 + 32 + j]};
        B2[p] = half2v{(_Float16)tab[960 + c0 * 96 + 64 + j], (_Float16)tab[960 + c1 * 96 + 64 + j]};
        hb[p] = half2v{(_Float16)tab[1920 + c0 * 32 + j], (_Float16)tab[1920 + c1 * 32 + j]};
    }
    const half2v zero = half2v{(_Float16)0.f, (_Float16)0.f};

    int wid = blockIdx.x * 4 + (threadIdx.x >> 6);
    const int ws = gridDim.x * 4;

    int n = wid;
    if (n >= NN) return;
    int e0 = offs[n];
    int e1 = offs[n + 1];
    uint4 qn = xs[n];
    int n2 = n + ws;
    int e0n = 0, e1n = 0;
    if (n2 < NN) { e0n = offs[n2]; e1n = offs[n2 + 1]; }
    uint4 q;
    {
        int ee = e0 + lane;
        int r0 = (ee < e1) ? csr_row[ee] : 0;
        q = xs[r0];
    }

    while (true) {
        int n3 = n2 + ws;
        int e0n2 = 0, e1n2 = 0;
        if (n3 < NN) { e0n2 = offs[n3]; e1n2 = offs[n3 + 1]; }
        uint4 qn2 = make_uint4(0u, 0u, 0u, 0u);
        if (n2 < NN) qn2 = xs[n2];

        bool multi = (e1 - e0) > 64;
        int pb = multi ? (e0 + 64) : e0n;
        int pe = multi ? e1 : e1n;
        int ee2 = pb + lane;
        int rn = (ee2 < pe) ? csr_row[ee2] : 0;

        half2v pxn = bch((int)qn.x), pyn = bch((int)qn.y), pzn = bch((int)qn.z);
        half2v va[5], acc[5];
        float accf[10];
#pragma unroll
        for (int p = 0; p < 5; ++p) {
            va[p] = hb[p] + pxn * B0[p] + pyn * B1[p] + pzn * B2[p];
            acc[p] = zero;
            accf[2 * p] = 0.f;
            accf[2 * p + 1] = 0.f;
        }

        int c2 = e1 - e0;
        if (c2 > 64) c2 = 64;
        int t0 = 0;
        if ((c2 >> 1) >= 4) {
#pragma unroll
            for (int u = 0; u < 4; ++u) EC_PAIR(q, 2 * u + half);
            EC_FLUSH();
            t0 = 4;
        }
        uint4 qpre = xs[rn];
        EC_CHUNK_FROM(t0, q, c2);

        if (multi) {
            int base = e0 + 64;
            uint4 qc = qpre;
            while (true) {
                int cc = e1 - base;
                if (cc > 64) cc = 64;
                int nb = base + 64;
                bool m2 = nb < e1;
                int pb2 = m2 ? nb : e0n;
                int pe2 = m2 ? e1 : e1n;
                int ee3 = pb2 + lane;
                int rn2 = (ee3 < pe2) ? csr_row[ee3] : 0;
                uint4 qp2 = xs[rn2];
                EC_CHUNK_FROM(0, qc, cc);
                qc = qp2;
                if (!m2) break;
                base = nb;
            }
            qpre = qc;
        }

        // cross-half reduce: all lanes end with full accf[0..9]
#pragma unroll
        for (int c = 0; c < 10; ++c) accf[c] += __shfl_xor(accf[c], 32, 64);
        // packed contiguous row store (K-permuted layout): dword d = p*32 + jch,
        // lanes cover d = i*64 + lane for i=0,1 and d = 128 + lane (half0).
        unsigned* arow32 = (unsigned*)(aggh + (size_t)n * 320);
        half2v d0 = {(_Float16)accf[2 * half],     (_Float16)accf[2 * half + 1]};
        half2v d1 = {(_Float16)accf[4 + 2 * half], (_Float16)accf[4 + 2 * half + 1]};
        arow32[lane]      = __builtin_bit_cast(unsigned, d0);
        arow32[64 + lane] = __builtin_bit_cast(unsigned, d1);
        if (half == 0) {
            half2v d2 = {(_Float16)accf[8], (_Float16)accf[9]};
            arow32[128 + lane] = __builtin_bit_cast(unsigned, d2);
        }

        if (n2 >= NN) return;
        n = n2;
        n2 = n3;
        e0 = e0n; e1 = e1n;
        e0n = e0n2; e1n = e1n2;
        qn = qn2;
        q = qpre;
    }
}

// Fold via MFMA (plain fp16, 2 MFMA/kc) + fused xw1-init; writes y1 = h*dinv fp16.
__global__ __launch_bounds__(256) void fold_mfma(
    const _Float16* __restrict__ aggh, const _Float16* __restrict__ MfragG,
    const float4* __restrict__ xpad, const int* __restrict__ ideg,
    const float* __restrict__ tab, const float* __restrict__ g1W,
    _Float16* __restrict__ y1) {
    __shared__ _Float16 Mf[10240];
    {
        const uint4* src = (const uint4*)MfragG;
        uint4* dst = (uint4*)Mf;
        for (int i = threadIdx.x; i < 1280; i += 256) dst[i] = src[i];
    }
    __syncthreads();

    int wave = blockIdx.x * 4 + (threadIdx.x >> 6);
    int lane = threadIdx.x & 63;
    int n0 = wave * 16;
    if (n0 >= NN) return;

    int m = lane & 15, q = lane >> 4;
    int arow_n = n0 + m;
    bool rowok = arow_n < NN;
    const _Float16* arow = aggh + (size_t)arow_n * 320 + q * 8;

    const half8* mf = (const half8*)Mf;
    f32x4 acc0 = {0.f, 0.f, 0.f, 0.f};
    f32x4 acc1 = {0.f, 0.f, 0.f, 0.f};

    for (int kc = 0; kc < 10; ++kc) {
        half8 a;
        if (rowok) a = *(const half8*)(arow + kc * 32);
        else {
#pragma unroll
            for (int i = 0; i < 8; ++i) a[i] = (_Float16)0.f;
        }
        half8 b0 = mf[(kc * 2 + 0) * 64 + lane];
        half8 b1 = mf[(kc * 2 + 1) * 64 + lane];
        acc0 = __builtin_amdgcn_mfma_f32_16x16x32_f16(a, b0, acc0, 0, 0, 0);
        acc1 = __builtin_amdgcn_mfma_f32_16x16x32_f16(a, b1, acc1, 0, 0, 0);
    }

    int jcol = lane & 15;
    float t0 = tab[12480 + jcol],      t1 = tab[12480 + 16 + jcol];
    float w00 = g1W[jcol],      w01 = g1W[32 + jcol],      w02 = g1W[64 + jcol];
    float w10 = g1W[16 + jcol], w11 = g1W[48 + jcol],      w12 = g1W[80 + jcol];
#pragma unroll
    for (int r = 0; r < 4; ++r) {
        int node = n0 + q * 4 + r;
        if (node < NN) {
            float4 xn = xpad[node];
            float dg = (float)ideg[node];
            float v0 = dg * t0 + xn.x * w00 + xn.y * w01 + xn.z * w02 + acc0[r];
            float v1 = dg * t1 + xn.x * w10 + xn.y * w11 + xn.z * w12 + acc1[r];
            y1[node * 32 + jcol]      = (_Float16)(v0 * xn.w);
            y1[node * 32 + 16 + jcol] = (_Float16)(v1 * xn.w);
        }
    }
}

// prop1 + fused xw2: 4 nodes/wave, 16 lanes/node, double-buffered gather groups.
__global__ __launch_bounds__(256, 8) void prop1_fused(
    const int* __restrict__ offs, const int* __restrict__ csr_row,
    const unsigned int* __restrict__ y1p, const float* __restrict__ dinv,
    const float* __restrict__ g1b, const float* __restrict__ g2W,
    unsigned int* __restrict__ y2p) {
    __shared__ float g2s[1024];
    for (int i = threadIdx.x; i < 1024; i += 256) g2s[i] = g2W[i];
    __syncthreads();

    int lane = threadIdx.x & 63;
    int l = lane & 15;
    int wid = blockIdx.x * 4 + (threadIdx.x >> 6);
    int n = wid * 4 + (lane >> 4);
    if (n >= NN) return;

    int e0 = offs[n], e1 = offs[n + 1];
    float di = dinv[n];
    half2v pn = __builtin_bit_cast(half2v, y1p[n * 16 + l]);
    float sAl = 0.f, sAh = 0.f, sBl = 0.f, sBh = 0.f;
    int e = e0;
    if (e + 7 < e1) {
        half2v p0[8];
        {
            int r0[8];
#pragma unroll
            for (int u = 0; u < 8; ++u) r0[u] = csr_row[e + u];
#pragma unroll
            for (int u = 0; u < 8; ++u) p0[u] = __builtin_bit_cast(half2v, y1p[r0[u] * 16 + l]);
        }
        while (true) {
            int e2 = e + 8;
            bool more = (e2 + 7 < e1);
            half2v p1[8];
            if (more) {
                int r1[8];
#pragma unroll
                for (int u = 0; u < 8; ++u) r1[u] = csr_row[e2 + u];
#pragma unroll
                for (int u = 0; u < 8; ++u) p1[u] = __builtin_bit_cast(half2v, y1p[r1[u] * 16 + l]);
            }
#pragma unroll
            for (int u = 0; u < 8; u += 2) {
                sAl += (float)p0[u].x;     sAh += (float)p0[u].y;
                sBl += (float)p0[u + 1].x; sBh += (float)p0[u + 1].y;
            }
            e = e2;
            if (!more) break;
#pragma unroll
            for (int u = 0; u < 8; ++u) p0[u] = p1[u];
        }
    }
    if (e + 3 < e1) {
        int r[4];
#pragma unroll
        for (int u = 0; u < 4; ++u) r[u] = csr_row[e + u];
        half2v p[4];
#pragma unroll
        for (int u = 0; u < 4; ++u) p[u] = __builtin_bit_cast(half2v, y1p[r[u] * 16 + l]);
        sAl += (float)p[0].x + (float)p[2].x; sAh += (float)p[0].y + (float)p[2].y;
        sBl += (float)p[1].x + (float)p[3].x; sBh += (float)p[1].y + (float)p[3].y;
        e += 4;
    }
    if (e + 1 < e1) {
        int r0 = csr_row[e], r1 = csr_row[e + 1];
        half2v p0 = __builtin_bit_cast(half2v, y1p[r0 * 16 + l]);
        half2v p1 = __builtin_bit_cast(half2v, y1p[r1 * 16 + l]);
        sAl += (float)p0.x; sAh += (float)p0.y;
        sBl += (float)p1.x; sBh += (float)p1.y;
        e += 2;
    }
    if (e < e1) {
        int r = csr_row[e];
        half2v p = __builtin_bit_cast(half2v, y1p[r * 16 + l]);
        sAl += (float)p.x; sAh += (float)p.y;
    }
    float h1l = di * (sAl + sBl + (float)pn.x);
    float h1h = di * (sAh + sBh + (float)pn.y);
    float hl = fmaxf(h1l + g1b[2 * l], 0.f);
    float hh = fmaxf(h1h + g1b[2 * l + 1], 0.f);

    float al = 0.f, ah = 0.f;
    int base = lane & 48;
#pragma unroll
    for (int m = 0; m < 16; ++m) {
        float xl = __shfl(hl, base + m, 64);
        float xh2 = __shfl(hh, base + m, 64);
        al += xl * g2s[(2 * m) * 32 + 2 * l] + xh2 * g2s[(2 * m + 1) * 32 + 2 * l];
        ah += xl * g2s[(2 * m) * 32 + 2 * l + 1] + xh2 * g2s[(2 * m + 1) * 32 + 2 * l + 1];
    }
    half2v o = {(_Float16)(al * di), (_Float16)(ah * di)};
    y2p[n * 16 + l] = __builtin_bit_cast(unsigned int, o);
}

// prop2 slot layout: 1 node/wave, lane = (edge-slot 0..3, channel 0..15).
__global__ __launch_bounds__(256, 8) void prop2_slot(
    const int* __restrict__ offs, const int* __restrict__ csr_row,
    const unsigned int* __restrict__ y2p, const float* __restrict__ dinv,
    unsigned int* __restrict__ outp) {
    int lane = threadIdx.x & 63;
    int l = lane & 15;
    int slot = lane >> 4;
    int n = blockIdx.x * 4 + (threadIdx.x >> 6);
    if (n >= NN) return;

    int e0 = offs[n], e1 = offs[n + 1];
    float di = dinv[n];
    half2v pn = __builtin_bit_cast(half2v, y2p[n * 16 + l]);
    float sl = 0.f, sh = 0.f;
    int e = e0;
    if (e < e1) {
        int i0 = e + slot, i1 = e + 4 + slot;
        int rA = csr_row[(i0 < e1) ? i0 : (e1 - 1)];
        int rB = csr_row[(i1 < e1) ? i1 : (e1 - 1)];
        bool okA = i0 < e1, okB = i1 < e1;
        while (true) {
            half2v pA = __builtin_bit_cast(half2v, y2p[rA * 16 + l]);
            half2v pB = __builtin_bit_cast(half2v, y2p[rB * 16 + l]);
            int en = e + 8;
            bool more = en < e1;
            int rA2 = 0, rB2 = 0;
            bool okA2 = false, okB2 = false;
            if (more) {
                int j0 = en + slot, j1 = en + 4 + slot;
                rA2 = csr_row[(j0 < e1) ? j0 : (e1 - 1)];
                rB2 = csr_row[(j1 < e1) ? j1 : (e1 - 1)];
                okA2 = j0 < e1; okB2 = j1 < e1;
            }
            if (okA) { sl += (float)pA.x; sh += (float)pA.y; }
            if (okB) { sl += (float)pB.x; sh += (float)pB.y; }
            e = en;
            if (!more) break;
            rA = rA2; rB = rB2; okA = okA2; okB = okB2;
        }
    }
    sl += __shfl_xor(sl, 16, 64); sl += __shfl_xor(sl, 32, 64);
    sh += __shfl_xor(sh, 16, 64); sh += __shfl_xor(sh, 32, 64);
    if (slot == 0) {
        half2v o = {(_Float16)(di * (sl + (float)pn.x)),
                    (_Float16)(di * (sh + (float)pn.y))};
        outp[n * 16 + l] = __builtin_bit_cast(unsigned int, o);
    }
}

__global__ void pool_seg(const _Float16* __restrict__ h2, const float* __restrict__ g2b,
                         const int* __restrict__ batch, float* __restrict__ pooled,
                         float* __restrict__ counts) {
    int grp = threadIdx.x >> 5, j = threadIdx.x & 31;
    int base = (blockIdx.x * 8 + grp) * 64;
    if (base >= NN) return;
    float bj = g2b[j];
    float acc = 0.f, cnt = 0.f;
    int curg = -1;
    int lim = base + 64;
    if (lim > NN) lim = NN;
    for (int n = base; n < lim; ++n) {
        int g = batch[n];
        if (g != curg) {
            if (curg >= 0) {
                atomicAdd(&pooled[curg * 32 + j], acc);
                if (j == 0) atomicAdd(&counts[curg], cnt);
            }
            curg = g; acc = 0.f; cnt = 0.f;
        }
        acc += fmaxf((float)h2[n * 32 + j] + bj, 0.f);
        cnt += 1.f;
    }
    if (curg >= 0) {
        atomicAdd(&pooled[curg * 32 + j], acc);
        if (j == 0) atomicAdd(&counts[curg], cnt);
    }
}

__global__ void final_kernel(const float* __restrict__ pooled, const float* __restrict__ counts,
                             const float* __restrict__ clsW, const float* __restrict__ clsb,
                             float* __restrict__ out) {
    int tid = threadIdx.x;
    if (tid >= GG * CC) return;
    int g = tid / CC, cc = tid % CC;
    float inv = 1.0f / fmaxf(counts[g], 1.0f);
    float s = clsb[cc];
    for (int j = 0; j < 32; ++j) s += (pooled[g * 32 + j] * inv) * clsW[j * CC + cc];
    out[g * CC + cc] = s;
}

extern "C" void kernel_launch(void* const* d_in, const int* in_sizes, int n_in,
                              void* d_out, int out_size, void* d_ws, size_t ws_size,
                              hipStream_t stream) {
    const float* x     = (const float*)d_in[0];
    const int*   ei    = (const int*)d_in[1];
    const int*   batch = (const int*)d_in[2];
    const float* fW    = (const float*)d_in[3];
    const float* fb    = (const float*)d_in[4];
    const float* W1    = (const float*)d_in[5];
    const float* b1    = (const float*)d_in[6];
    const float* W2    = (const float*)d_in[7];
    const float* b2    = (const float*)d_in[8];
    const float* g1W   = (const float*)d_in[9];
    const float* g1b   = (const float*)d_in[10];
    const float* g2W   = (const float*)d_in[11];
    const float* g2b   = (const float*)d_in[12];
    const float* clsW  = (const float*)d_in[13];
    const float* clsb  = (const float*)d_in[14];
    float* out = (float*)d_out;

    float4*         xpad    = (float4*)d_ws;                          // 1.6 MB
    uint4*          xs      = (uint4*)(xpad + NN);                    // 1.6 MB (fp16 splats)
    _Float16*       aggh    = (_Float16*)(xs + NN);                   // 64 MB
    unsigned int*   part    = (unsigned int*)aggh;                    // ALIAS: build-phase only
    int*            csr_row = (int*)(aggh + (size_t)NN * 320);        // 6.4 MB
    int*            mat     = (int*)(csr_row + NE);
    int*            msum    = mat + MTOT;
    int*            ideg    = msum + 256;
    int*            offs    = ideg + NN;
    float*          dinv    = (float*)(offs + NN + 1);
    float*          tab     = dinv + NN;
    _Float16*       Mfrag   = (_Float16*)(tab + 16384);               // 20 KB
    _Float16*       y1      = Mfrag + 10240;                          // 6.4 MB
    unsigned int*   y2p     = (unsigned int*)(y1 + (size_t)NN * 32);  // 6.4 MB
    unsigned int*   h2p     = y2p + (size_t)NN * 16;                  // 6.4 MB
    float*          pooled  = (float*)(h2p + (size_t)NN * 16);
    float*          counts  = pooled + GG * 32;

    const int propBlocks = (NN + 15) / 16;
    const int foldBlocks = ((NN + 15) / 16 + 3) / 4;
    const int slotBlocks = (NN + 3) / 4;

    precompute_small<<<10, 1024, 0, stream>>>(fW, fb, W1, b1, W2, b2, g1W, tab, Mfrag);

    bucket_hist<<<PBLK, 256, 0, stream>>>(ei, mat);
    scan_m1<<<MSB, 256, 0, stream>>>(mat, msum);
    scan_m2<<<1, 256, 0, stream>>>(msum, pooled);
    scan_m3<<<MSB, 256, 0, stream>>>(mat, msum);
    bucket_scatter<<<PBLK, 256, 0, stream>>>(ei, mat, part);
    bucket_build<<<NB, 256, 0, stream>>>(part, mat, x, csr_row, ideg, offs, dinv, xpad, xs);

    edgeconv_fused<<<2048, 256, 0, stream>>>(xs, offs, csr_row, tab, aggh);
    fold_mfma<<<foldBlocks, 256, 0, stream>>>(aggh, Mfrag, xpad, ideg, tab, g1W, y1);

    prop1_fused<<<propBlocks, 256, 0, stream>>>(offs, csr_row, (const unsigned int*)y1,
                                                dinv, g1b, g2W, y2p);
    prop2_slot<<<slotBlocks, 256, 0, stream>>>(offs, csr_row, y2p, dinv, h2p);
    pool_seg<<<(NN + 511) / 512, 256, 0, stream>>>((const _Float16*)h2p, g2b, batch,
                                                   pooled, counts);
    final_kernel<<<1, 640, 0, stream>>>(pooled, counts, clsW, clsb, out);
}